// Round 8
// baseline (236.511 us; speedup 1.0000x reference)
//
#include <hip/hip_runtime.h>
#include <hip/hip_fp16.h>
#include <math.h>

// MaxSim contrastive loss, MI355X — global_load_lds 2-phase counted pipeline.
// Round-7 lesson: reg-staged asm pipeline failed correctness (vmcnt ledger
// fragility). This round: every component individually verified —
//  * staging: round-2's global_load_lds + XOR-pre-swizzled SOURCE (absmax 0.0)
//  * sync: guide's minimal 2-phase template: STAGE(next buf) issued BEFORE
//    compute(cur), single vmcnt(0)+barrier per tile at END of compute so the
//    stage loads get a full compute phase (~6000cy) of flight (round 2's bug
//    was draining immediately after issue via __syncthreads).
//  * norms: recomputed from the fragment ds_reads (designated waves), since
//    data no longer passes through registers.
// fp32 LDS 2x32KB dbuf, 512 threads, 2 blocks/CU, 16 waves/CU.

constexpr int NB = 128;
constexpr int LQ = 256;
constexpr int LK = 512;
constexpr int DD = 1024;

#define TEMP_INV 20.0f
#define EPSN 1e-12f

typedef __fp16 fp16x2 __attribute__((ext_vector_type(2)));   // cvt_pkrtz return
typedef _Float16 f16x8 __attribute__((ext_vector_type(8)));  // MFMA operand
typedef float f32x4 __attribute__((ext_vector_type(4)));

#define BM 128
#define BN 128
#define BK 32
#define NT (DD / BK)   // 32

__device__ __forceinline__ f16x8 cvt8(f32x4 a, f32x4 b) {
  union { f16x8 v; fp16x2 h[4]; } u;
  u.h[0] = __builtin_amdgcn_cvt_pkrtz(a[0], a[1]);
  u.h[1] = __builtin_amdgcn_cvt_pkrtz(a[2], a[3]);
  u.h[2] = __builtin_amdgcn_cvt_pkrtz(b[0], b[1]);
  u.h[3] = __builtin_amdgcn_cvt_pkrtz(b[2], b[3]);
  return u.v;
}

__device__ __forceinline__ void gload16(const float* g, void* l) {
  __builtin_amdgcn_global_load_lds(
      (const __attribute__((address_space(1))) void*)g,
      (__attribute__((address_space(3))) void*)l, 16, 0, 0);
}

#define WAIT_ALL asm volatile("s_waitcnt vmcnt(0) lgkmcnt(0)" ::: "memory")
#define SB()     __builtin_amdgcn_sched_barrier(0)
#define FENCE    asm volatile("" ::: "memory")

__global__ __launch_bounds__(512, 4) void maxsim_kernel(
    const float* __restrict__ q, const float* __restrict__ pk,
    const float* __restrict__ nk, const int* __restrict__ pmask,
    const int* __restrict__ nmask, float* __restrict__ part) {
  __shared__ float __align__(16) Asb[2][BM * BK];  // 2 x 16 KB
  __shared__ float __align__(16) Bsb[2][BN * BK];  // 2 x 16 KB

  const int x = blockIdx.x;
  const int b = blockIdx.y;
  const int mt = x >> 3;         // 0..1  (q tile)
  const int nt = (x >> 1) & 3;   // 0..3  (key tile)
  const int kt = x & 1;          // 0=pos 1=neg

  const float* kbase = kt ? nk : pk;
  const int* mbase = kt ? nmask : pmask;

  const float* Ag = q + ((size_t)b * LQ + mt * BM) * DD;
  const float* Bg = kbase + ((size_t)b * LK + nt * BN) * DD;

  const int tid = threadIdx.x;
  const int lane = tid & 63;
  const int w = tid >> 6;        // 0..7
  const int wr = w >> 1;         // 0..3 : A rows wr*32 + [0,32)
  const int wc = w & 1;          // 0..1 : B rows wc*64 + [0,64)
  const int frow = lane & 15;
  const int kgrp = lane >> 4;    // 0..3

  // staging: thread t stages 16B chunk (t&7) of row (t>>3)+64h; the SOURCE
  // chunk is pre-XOR-swizzled so the linear LDS dest ends up swizzled
  // (global_load_lds dest must stay linear — rule #21, verified round 2).
  const int srow = tid >> 3;     // 0..63
  const int sgrp = tid & 7;
  const int gsrc = sgrp ^ (srow & 7);   // (srow+64)&7 == srow&7

  float ssqA[2] = {0.f, 0.f};          // valid on wc==0 waves
  float ssqB[4] = {0.f, 0.f, 0.f, 0.f}; // valid on wr==0 waves
  f32x4 acc[2][4] = {};

  auto STAGE = [&](int sel, int t) {
    const int koff = t * BK;
    gload16(Ag + (size_t)srow * DD + koff + gsrc * 4,
            (char*)&Asb[sel][0] + w * 1024);
    gload16(Ag + (size_t)(srow + 64) * DD + koff + gsrc * 4,
            (char*)&Asb[sel][0] + 8192 + w * 1024);
    gload16(Bg + (size_t)srow * DD + koff + gsrc * 4,
            (char*)&Bsb[sel][0] + w * 1024);
    gload16(Bg + (size_t)(srow + 64) * DD + koff + gsrc * 4,
            (char*)&Bsb[sel][0] + 8192 + w * 1024);
  };

  auto COMPUTE = [&](int sel) {
    f16x8 af[2], bf[4];
    #pragma unroll
    for (int m = 0; m < 2; ++m) {
      const int row = wr * 32 + m * 16 + frow;
      const int sw = row & 7;
      f32x4 x0 = *(const f32x4*)&Asb[sel][row * BK + (((2 * kgrp) ^ sw) << 2)];
      f32x4 x1 = *(const f32x4*)&Asb[sel][row * BK + (((2 * kgrp + 1) ^ sw) << 2)];
      if (wc == 0)
        ssqA[m] += x0[0]*x0[0]+x0[1]*x0[1]+x0[2]*x0[2]+x0[3]*x0[3]
                 + x1[0]*x1[0]+x1[1]*x1[1]+x1[2]*x1[2]+x1[3]*x1[3];
      af[m] = cvt8(x0, x1);
    }
    #pragma unroll
    for (int n = 0; n < 4; ++n) {
      const int row = wc * 64 + n * 16 + frow;
      const int sw = row & 7;
      f32x4 y0 = *(const f32x4*)&Bsb[sel][row * BK + (((2 * kgrp) ^ sw) << 2)];
      f32x4 y1 = *(const f32x4*)&Bsb[sel][row * BK + (((2 * kgrp + 1) ^ sw) << 2)];
      if (wr == 0)
        ssqB[n] += y0[0]*y0[0]+y0[1]*y0[1]+y0[2]*y0[2]+y0[3]*y0[3]
                 + y1[0]*y1[0]+y1[1]*y1[1]+y1[2]*y1[2]+y1[3]*y1[3];
      bf[n] = cvt8(y0, y1);
    }
    #pragma unroll
    for (int m = 0; m < 2; ++m)
      #pragma unroll
      for (int n = 0; n < 4; ++n)
        acc[m][n] = __builtin_amdgcn_mfma_f32_16x16x32_f16(af[m], bf[n], acc[m][n], 0, 0, 0);
  };

  // prologue
  STAGE(0, 0);
  WAIT_ALL; SB(); __builtin_amdgcn_s_barrier(); FENCE; SB();

  int sel = 0;
  for (int t = 0; t < NT - 1; ++t) {
    STAGE(sel ^ 1, t + 1);   // issue BEFORE compute — flies during MFMA phase
    COMPUTE(sel);
    WAIT_ALL;                // my ds_reads done + my stage loads landed
    SB(); __builtin_amdgcn_s_barrier(); FENCE; SB();
    sel ^= 1;
  }
  COMPUTE(sel);              // tile 31 from buf1

  // ---- epilogue: norms from fragment reads, column scales, row-max ----
  // reduce ssq over the 4 kgrp lanes sharing each row (lane bits 4,5)
  if (wc == 0) {
    #pragma unroll
    for (int m = 0; m < 2; ++m) {
      ssqA[m] += __shfl_xor(ssqA[m], 16);
      ssqA[m] += __shfl_xor(ssqA[m], 32);
    }
  }
  if (wr == 0) {
    #pragma unroll
    for (int n = 0; n < 4; ++n) {
      ssqB[n] += __shfl_xor(ssqB[n], 16);
      ssqB[n] += __shfl_xor(ssqB[n], 32);
    }
  }

  // aux aliased onto Asb[0]: final COMPUTE reads only buf1; no DMA pending.
  float* const aux = reinterpret_cast<float*>(&Asb[0][0]);
  float* const csc = aux;             // [BN]  (1/|k|)*mask
  float* const invA_s = aux + BN;     // [BM]  1/|q|
  float* const rmax = aux + BN + BM;  // [BM][2]

  if (wc == 0 && lane < 16) {
    #pragma unroll
    for (int m = 0; m < 2; ++m)
      invA_s[wr * 32 + m * 16 + lane] = 1.0f / fmaxf(sqrtf(ssqA[m]), EPSN);
  }
  if (wr == 0 && lane < 16) {
    #pragma unroll
    for (int n = 0; n < 4; ++n) {
      const int row = wc * 64 + n * 16 + lane;
      const int key = nt * BN + row;
      csc[row] = (mbase[(size_t)b * LK + key] ? 1.0f : 0.0f) /
                 fmaxf(sqrtf(ssqB[n]), EPSN);
    }
  }
  __syncthreads();

  float vmax[2][4];
  #pragma unroll
  for (int m = 0; m < 2; ++m)
    #pragma unroll
    for (int r = 0; r < 4; ++r) vmax[m][r] = -INFINITY;
  #pragma unroll
  for (int n = 0; n < 4; ++n) {
    const float s = csc[wc * 64 + n * 16 + frow];
    #pragma unroll
    for (int m = 0; m < 2; ++m)
      #pragma unroll
      for (int r = 0; r < 4; ++r)
        vmax[m][r] = fmaxf(vmax[m][r], acc[m][n][r] * s);
  }
  #pragma unroll
  for (int off = 1; off < 16; off <<= 1)
    #pragma unroll
    for (int m = 0; m < 2; ++m)
      #pragma unroll
      for (int r = 0; r < 4; ++r)
        vmax[m][r] = fmaxf(vmax[m][r], __shfl_xor(vmax[m][r], off));
  if ((lane & 15) == 0) {
    #pragma unroll
    for (int m = 0; m < 2; ++m)
      #pragma unroll
      for (int r = 0; r < 4; ++r)
        rmax[(wr * 32 + m * 16 + kgrp * 4 + r) * 2 + wc] = vmax[m][r];
  }
  __syncthreads();
  if (tid < BM) {
    const float v = fmaxf(rmax[tid * 2], rmax[tid * 2 + 1]) * invA_s[tid];
    part[(((size_t)kt * NB + b) * 4 + nt) * LQ + mt * BM + tid] = v;
  }
}

// ---------------- logits + softplus per batch ----------------
__global__ __launch_bounds__(256) void logits_kernel(
    const float* __restrict__ part, const int* __restrict__ qmask,
    float* __restrict__ nll) {
  int b = blockIdx.x;
  int t = threadIdx.x;  // = lq
  float mp = -INFINITY, mn = -INFINITY;
  #pragma unroll
  for (int ntile = 0; ntile < 4; ++ntile) {
    mp = fmaxf(mp, part[(((size_t)0 * NB + b) * 4 + ntile) * LQ + t]);
    mn = fmaxf(mn, part[(((size_t)1 * NB + b) * 4 + ntile) * LQ + t]);
  }
  float qm = qmask[(size_t)b * LQ + t] ? 1.0f : 0.0f;
  float p = mp * qm;  // 1/|q| already folded into part
  float n = mn * qm;
  #pragma unroll
  for (int o = 32; o; o >>= 1) { p += __shfl_down(p, o); n += __shfl_down(n, o); }
  __shared__ float sp[4], sn[4];
  int lane = t & 63, w = t >> 6;
  if (lane == 0) { sp[w] = p; sn[w] = n; }
  __syncthreads();
  if (t == 0) {
    float ps = sp[0] + sp[1] + sp[2] + sp[3];
    float ns = sn[0] + sn[1] + sn[2] + sn[3];
    float z = (ns - ps) * TEMP_INV;
    nll[b] = z > 0.0f ? z + log1pf(expf(-z)) : log1pf(expf(z));
  }
}

__global__ void finalize_kernel(const float* __restrict__ nll, float* __restrict__ out) {
  __shared__ float s[128];
  int t = threadIdx.x;
  s[t] = nll[t];
  __syncthreads();
  #pragma unroll
  for (int o = 64; o; o >>= 1) {
    if (t < o) s[t] += s[t + o];
    __syncthreads();
  }
  if (t == 0) out[0] = s[0] * (1.0f / 128.0f);
}

extern "C" void kernel_launch(void* const* d_in, const int* in_sizes, int n_in,
                              void* d_out, int out_size, void* d_ws, size_t ws_size,
                              hipStream_t stream) {
  const float* q = (const float*)d_in[0];
  const float* pk = (const float*)d_in[1];
  const float* nk = (const float*)d_in[2];
  const int* qm = (const int*)d_in[3];
  const int* pm = (const int*)d_in[4];
  const int* nm = (const int*)d_in[5];

  float* ws = (float*)d_ws;
  float* part = ws;                // 262144 floats: [kt][b][nt][lq]
  float* nll = part + 262144;      // 128 floats

  maxsim_kernel<<<dim3(16, NB, 1), 512, 0, stream>>>(q, pk, nk, pm, nm, part);
  logits_kernel<<<NB, 256, 0, stream>>>(part, qm, nll);
  finalize_kernel<<<1, 128, 0, stream>>>(nll, (float*)d_out);
}

// Round 9
// 226.890 us; speedup vs baseline: 1.0424x; 1.0424x over previous
//
#include <hip/hip_runtime.h>
#include <hip/hip_fp16.h>
#include <math.h>

// MaxSim contrastive loss, MI355X.
// Round-9: round-6's verified f16-LDS/BK=64/XOR-swizzled reg-staged GEMM
// (absmax 0.0) with the staging loads pinned as inline-asm volatile
// global_load_dwordx4 (cannot be sunk — rounds 3-6 failure) and a DRAIN-ALL
// s_waitcnt vmcnt(0) placed between COMPUTE and STORE (spill-immune — round-7
// counted-vmcnt failure). Loads issue before COMPUTE, fly under the MFMAs,
// drain after. Round-8 showed the gload_lds/fp32-LDS alternative is
// LDS-bandwidth-bound (192KB reads/CU/step ~= 100% LDS duty); f16 tiles
// halve LDS read bytes and do cvt once at staging.

constexpr int NB = 128;
constexpr int LQ = 256;
constexpr int LK = 512;
constexpr int DD = 1024;

#define TEMP_INV 20.0f
#define EPSN 1e-12f

typedef __fp16 fp16x2 __attribute__((ext_vector_type(2)));   // cvt_pkrtz return
typedef _Float16 f16x8 __attribute__((ext_vector_type(8)));  // MFMA operand
typedef float f32x4 __attribute__((ext_vector_type(4)));

#define BM 128
#define BN 128
#define BK 64
#define KITERS (DD / BK)   // 16

__device__ __forceinline__ f16x8 cvt8(f32x4 a, f32x4 b) {
  union { f16x8 v; fp16x2 h[4]; } u;
  u.h[0] = __builtin_amdgcn_cvt_pkrtz(a[0], a[1]);
  u.h[1] = __builtin_amdgcn_cvt_pkrtz(a[2], a[3]);
  u.h[2] = __builtin_amdgcn_cvt_pkrtz(b[0], b[1]);
  u.h[3] = __builtin_amdgcn_cvt_pkrtz(b[2], b[3]);
  return u.v;
}

// pinned async 32B load (2x dwordx4). asm volatile + memory clobber: cannot
// be sunk below program-order memory ops; results are NOT ready until our
// explicit s_waitcnt vmcnt(0).
__device__ __forceinline__ void gld2(f32x4& d0, f32x4& d1, const float* p) {
  asm volatile("global_load_dwordx4 %0, %2, off\n\t"
               "global_load_dwordx4 %1, %2, off offset:16"
               : "=&v"(d0), "=&v"(d1)
               : "v"(p)
               : "memory");
}
#define WAITV0 asm volatile("s_waitcnt vmcnt(0)" ::: "memory")
#define SB()   __builtin_amdgcn_sched_barrier(0)

__global__ __launch_bounds__(512, 4) void maxsim_kernel(
    const float* __restrict__ q, const float* __restrict__ pk,
    const float* __restrict__ nk, const int* __restrict__ pmask,
    const int* __restrict__ nmask, float* __restrict__ part) {
  __shared__ _Float16 __align__(16) As[2][BM * BK];  // 32 KB
  __shared__ _Float16 __align__(16) Bs[2][BN * BK];  // 32 KB

  const int x = blockIdx.x;
  const int b = blockIdx.y;
  const int mt = x >> 3;         // 0..1  (q tile)
  const int nt = (x >> 1) & 3;   // 0..3  (key tile)
  const int kt = x & 1;          // 0=pos 1=neg

  const float* kbase = kt ? nk : pk;
  const int* mbase = kt ? nmask : pmask;

  const float* Ag = q + ((size_t)b * LQ + mt * BM) * DD;
  const float* Bg = kbase + ((size_t)b * LK + nt * BN) * DD;

  const int tid = threadIdx.x;
  const int lane = tid & 63;
  const int w = tid >> 6;        // 0..7
  const int wr = w >> 1;         // 0..3 : A rows wr*32 + [0,32)
  const int wc = w & 1;          // 0..1 : B rows wc*64 + [0,64)
  const int frow = lane & 15;
  const int kgrp = lane >> 4;    // 0..3

  // staging map: thread t -> rows (t>>3)+64i (i=0..1), 16B chunk c = t&7
  const int srow0 = tid >> 3;    // 0..63
  const int sc = tid & 7;        // chunk of 8 cols

  const float* pa0 = Ag + (size_t)srow0 * DD + sc * 8;
  const float* pa1 = Ag + (size_t)(srow0 + 64) * DD + sc * 8;
  const float* pb0 = Bg + (size_t)srow0 * DD + sc * 8;
  const float* pb1 = Bg + (size_t)(srow0 + 64) * DD + sc * 8;

  float ssqA[2] = {0.f, 0.f};
  float ssqB[2] = {0.f, 0.f};
  f32x4 acc[2][4] = {};
  // staged tile registers — live across COMPUTE (that's the whole point)
  f32x4 a00, a01, a10, a11, b00, b01, b10, b11;

  auto GLD = [&](int t) {
    const int koff = t * BK;
    gld2(a00, a01, pa0 + koff);
    gld2(a10, a11, pa1 + koff);
    gld2(b00, b01, pb0 + koff);
    gld2(b10, b11, pb1 + koff);
  };
  auto sq8 = [](f32x4 u, f32x4 v) {
    return u[0]*u[0]+u[1]*u[1]+u[2]*u[2]+u[3]*u[3] +
           v[0]*v[0]+v[1]*v[1]+v[2]*v[2]+v[3]*v[3];
  };
  auto STORE = [&](int bsel) {
    ssqA[0] += sq8(a00, a01);
    ssqA[1] += sq8(a10, a11);
    ssqB[0] += sq8(b00, b01);
    ssqB[1] += sq8(b10, b11);
    const int cofs0 = ((sc ^ (srow0 & 7)) << 3);   // (srow0+64)&7 == srow0&7
    *(f16x8*)&As[bsel][srow0 * BK + cofs0] = cvt8(a00, a01);
    *(f16x8*)&As[bsel][(srow0 + 64) * BK + cofs0] = cvt8(a10, a11);
    *(f16x8*)&Bs[bsel][srow0 * BK + cofs0] = cvt8(b00, b01);
    *(f16x8*)&Bs[bsel][(srow0 + 64) * BK + cofs0] = cvt8(b10, b11);
  };
  auto COMPUTE = [&](int bsel) {
    #pragma unroll
    for (int ks = 0; ks < 2; ++ks) {
      const int ch = ks * 4 + kgrp;
      f16x8 af[2], bf[4];
      #pragma unroll
      for (int m = 0; m < 2; ++m) {
        const int row = wr * 32 + m * 16 + frow;
        af[m] = *(const f16x8*)&As[bsel][row * BK + ((ch ^ (row & 7)) << 3)];
      }
      #pragma unroll
      for (int n = 0; n < 4; ++n) {
        const int row = wc * 64 + n * 16 + frow;
        bf[n] = *(const f16x8*)&Bs[bsel][row * BK + ((ch ^ (row & 7)) << 3)];
      }
      #pragma unroll
      for (int m = 0; m < 2; ++m)
        #pragma unroll
        for (int n = 0; n < 4; ++n)
          acc[m][n] = __builtin_amdgcn_mfma_f32_16x16x32_f16(af[m], bf[n], acc[m][n], 0, 0, 0);
    }
  };

  // prologue: stage tile 0
  GLD(0);
  WAITV0; SB();
  STORE(0);
  __syncthreads();

  int buf = 0;
  for (int t = 0; t < KITERS - 1; ++t) {
    GLD(t + 1);        // pinned asm issue — flies during COMPUTE
    SB();
    COMPUTE(buf);
    WAITV0; SB();      // loads landed (had the whole MFMA phase in flight)
    STORE(buf ^ 1);
    __syncthreads();
    buf ^= 1;
  }
  COMPUTE(buf);        // final K-tile

  // ---- epilogue: norms, column scales, row-max (verified round 6) ----
  #pragma unroll
  for (int off = 1; off < 8; off <<= 1) {
    #pragma unroll
    for (int i = 0; i < 2; ++i) {
      ssqA[i] += __shfl_xor(ssqA[i], off);
      ssqB[i] += __shfl_xor(ssqB[i], off);
    }
  }

  // aux aliased onto As[0]; final COMPUTE read As[1]/Bs[1] only.
  float* const aux = reinterpret_cast<float*>(&As[0][0]);
  float* const csc = aux;             // [BN]  (1/|k|)*mask
  float* const invA_s = aux + BN;     // [BM]  1/|q|
  float* const rmax = aux + BN + BM;  // [BM][2]

  if (sc == 0) {
    #pragma unroll
    for (int i = 0; i < 2; ++i) {
      const int row = srow0 + 64 * i;
      invA_s[row] = 1.0f / fmaxf(sqrtf(ssqA[i]), EPSN);
      const int key = nt * BN + row;
      csc[row] = (mbase[(size_t)b * LK + key] ? 1.0f : 0.0f) /
                 fmaxf(sqrtf(ssqB[i]), EPSN);
    }
  }
  __syncthreads();

  float vmax[2][4];
  #pragma unroll
  for (int m = 0; m < 2; ++m)
    #pragma unroll
    for (int r = 0; r < 4; ++r) vmax[m][r] = -INFINITY;
  #pragma unroll
  for (int n = 0; n < 4; ++n) {
    const float s = csc[wc * 64 + n * 16 + frow];
    #pragma unroll
    for (int m = 0; m < 2; ++m)
      #pragma unroll
      for (int r = 0; r < 4; ++r)
        vmax[m][r] = fmaxf(vmax[m][r], acc[m][n][r] * s);
  }
  #pragma unroll
  for (int off = 1; off < 16; off <<= 1)
    #pragma unroll
    for (int m = 0; m < 2; ++m)
      #pragma unroll
      for (int r = 0; r < 4; ++r)
        vmax[m][r] = fmaxf(vmax[m][r], __shfl_xor(vmax[m][r], off));
  if ((lane & 15) == 0) {
    #pragma unroll
    for (int m = 0; m < 2; ++m)
      #pragma unroll
      for (int r = 0; r < 4; ++r)
        rmax[(wr * 32 + m * 16 + kgrp * 4 + r) * 2 + wc] = vmax[m][r];
  }
  __syncthreads();
  if (tid < BM) {
    const float v = fmaxf(rmax[tid * 2], rmax[tid * 2 + 1]) * invA_s[tid];
    part[(((size_t)kt * NB + b) * 4 + nt) * LQ + mt * BM + tid] = v;
  }
}

// ---------------- logits + softplus per batch ----------------
__global__ __launch_bounds__(256) void logits_kernel(
    const float* __restrict__ part, const int* __restrict__ qmask,
    float* __restrict__ nll) {
  int b = blockIdx.x;
  int t = threadIdx.x;  // = lq
  float mp = -INFINITY, mn = -INFINITY;
  #pragma unroll
  for (int ntile = 0; ntile < 4; ++ntile) {
    mp = fmaxf(mp, part[(((size_t)0 * NB + b) * 4 + ntile) * LQ + t]);
    mn = fmaxf(mn, part[(((size_t)1 * NB + b) * 4 + ntile) * LQ + t]);
  }
  float qm = qmask[(size_t)b * LQ + t] ? 1.0f : 0.0f;
  float p = mp * qm;  // 1/|q| already folded into part
  float n = mn * qm;
  #pragma unroll
  for (int o = 32; o; o >>= 1) { p += __shfl_down(p, o); n += __shfl_down(n, o); }
  __shared__ float sp[4], sn[4];
  int lane = t & 63, w = t >> 6;
  if (lane == 0) { sp[w] = p; sn[w] = n; }
  __syncthreads();
  if (t == 0) {
    float ps = sp[0] + sp[1] + sp[2] + sp[3];
    float ns = sn[0] + sn[1] + sn[2] + sn[3];
    float z = (ns - ps) * TEMP_INV;
    nll[b] = z > 0.0f ? z + log1pf(expf(-z)) : log1pf(expf(z));
  }
}

__global__ void finalize_kernel(const float* __restrict__ nll, float* __restrict__ out) {
  __shared__ float s[128];
  int t = threadIdx.x;
  s[t] = nll[t];
  __syncthreads();
  #pragma unroll
  for (int o = 64; o; o >>= 1) {
    if (t < o) s[t] += s[t + o];
    __syncthreads();
  }
  if (t == 0) out[0] = s[0] * (1.0f / 128.0f);
}

extern "C" void kernel_launch(void* const* d_in, const int* in_sizes, int n_in,
                              void* d_out, int out_size, void* d_ws, size_t ws_size,
                              hipStream_t stream) {
  const float* q = (const float*)d_in[0];
  const float* pk = (const float*)d_in[1];
  const float* nk = (const float*)d_in[2];
  const int* qm = (const int*)d_in[3];
  const int* pm = (const int*)d_in[4];
  const int* nm = (const int*)d_in[5];

  float* ws = (float*)d_ws;
  float* part = ws;                // 262144 floats: [kt][b][nt][lq]
  float* nll = part + 262144;      // 128 floats

  maxsim_kernel<<<dim3(16, NB, 1), 512, 0, stream>>>(q, pk, nk, pm, nm, part);
  logits_kernel<<<NB, 256, 0, stream>>>(part, qm, nll);
  finalize_kernel<<<1, 128, 0, stream>>>(nll, (float*)d_out);
}